// Round 1
// baseline (186.307 us; speedup 1.0000x reference)
//
#include <hip/hip_runtime.h>

// RegionSelector: [B,1,512,512] f32 -> [B,1,2] int32 (row,col) argmax over
// 3x3 window sums of 4x4 grid-cell means. GRID=4, WIN=3 -> n=2,
// cell = 128x128. Mean scale is argmax-invariant -> use sums.
//
// History:
//  - Every cross-workgroup IN-KERNEL sync variant paid 100-400us in CDNA4
//    device-scope cache maintenance (R2 acquire-spin 457us, R3 relaxed-spin
//    stale-line 233us, R4 ACQ_REL ticket 152us).
//  - R5 (prev best, 185.6us): one block per batch, zero sync. rocprof showed
//    the kernel itself is only ~30us of that; ~156us is the harness's 2x
//    512MiB workspace-poison fills. But 128 blocks = half the CUs idle ->
//    kernel ran at ~4.5 TB/s instead of ~6.5.
//  - R6 (this): two-kernel split. Stream ordering between dispatches gives
//    cross-block coherence for FREE (no flags, no atomics, no spins).
//    Kernel 1: 512 blocks (B x 4 grid-row bands) x 1024 threads = 2 blocks/CU
//    on ALL 256 CUs, streams 134MB and writes 16 cell sums per batch to d_ws
//    (8KB, fully overwritten each iter -> poison-safe).
//    Kernel 2: trivial 3x3-window argmax per batch, ~8KB L2-resident reads.

#define H 512
#define W 512

__global__ __launch_bounds__(1024) void cell_sums(
    const float* __restrict__ src, float* __restrict__ ws) {
  const int b = blockIdx.x >> 2;   // batch
  const int gr = blockIdx.x & 3;   // grid row band (128 rows)
  const int t = threadIdx.x;
  const float4* base =
      (const float4*)(src + (size_t)b * (H * W) + (size_t)gr * 128 * W);

  // Band = 16384 float4. f = t + 1024*k -> col4 = f & 127 = t & 127 is
  // CONSTANT per thread -> fixed grid column gc = (t&127)>>5 -> a single
  // scalar accumulator, no indexed arrays.
  float s = 0.0f;
#pragma unroll
  for (int k = 0; k < 16; ++k) {
    float4 v = base[t + 1024 * k];
    s += (v.x + v.y) + (v.z + v.w);
  }

  // Within a 32-lane segment all lanes share gc (seg*32 % 128 = (seg&3)*32).
#pragma unroll
  for (int off = 16; off > 0; off >>= 1) s += __shfl_down(s, off, 32);

  __shared__ float seg_sums[32];  // [segment]; segment's gc = seg & 3
  const int seg = t >> 5;
  if ((t & 31) == 0) seg_sums[seg] = s;
  __syncthreads();

  // 8 segments per grid column; thread gc<4 sums its column's segments.
  if (t < 4) {
    float c = 0.0f;
#pragma unroll
    for (int j = 0; j < 8; ++j) c += seg_sums[j * 4 + t];
    ws[b * 16 + gr * 4 + t] = c;  // cell sum S[gr][gc=t]
  }
}

__global__ void finalize(const float* __restrict__ ws, int* __restrict__ out,
                         int B) {
  const int b = blockIdx.x * blockDim.x + threadIdx.x;
  if (b >= B) return;

  float S[16];
  const float4* w4 = (const float4*)(ws + (size_t)b * 16);
#pragma unroll
  for (int i = 0; i < 4; ++i) {
    float4 v = w4[i];
    S[i * 4 + 0] = v.x;
    S[i * 4 + 1] = v.y;
    S[i * 4 + 2] = v.z;
    S[i * 4 + 3] = v.w;
  }

  // 3x3 window sums, n=2; strict '>' keeps lowest flattened index on ties
  // (matches jax.lax.top_k).
  float best = -__builtin_inff();
  int bi = 0;
#pragma unroll
  for (int i = 0; i < 2; ++i)
#pragma unroll
    for (int j = 0; j < 2; ++j) {
      float wsum = 0.0f;
#pragma unroll
      for (int di = 0; di < 3; ++di)
#pragma unroll
        for (int dj = 0; dj < 3; ++dj) wsum += S[(i + di) * 4 + (j + dj)];
      if (wsum > best) {
        best = wsum;
        bi = i * 2 + j;
      }
    }
  out[b * 2 + 0] = bi >> 1;  // row
  out[b * 2 + 1] = bi & 1;   // col
}

extern "C" void kernel_launch(void* const* d_in, const int* in_sizes, int n_in,
                              void* d_out, int out_size, void* d_ws,
                              size_t ws_size, hipStream_t stream) {
  const float* src = (const float*)d_in[0];
  int* out = (int*)d_out;
  float* ws = (float*)d_ws;
  const int B = in_sizes[0] / (H * W);

  cell_sums<<<B * 4, 1024, 0, stream>>>(src, ws);
  finalize<<<(B + 127) / 128, 128, 0, stream>>>(ws, out, B);
}

// Round 2
// 180.868 us; speedup vs baseline: 1.0301x; 1.0301x over previous
//
#include <hip/hip_runtime.h>

// RegionSelector: [B,1,512,512] f32 -> [B,1,2] int32 (row,col) argmax over
// 3x3 window sums of 4x4 grid-cell means. GRID=4, WIN=3 -> n=2,
// cell = 128x128. Mean scale is argmax-invariant -> use sums.
//
// History:
//  - Cross-workgroup IN-KERNEL sync: 100-400us CDNA4 cache maintenance
//    (R2 acquire-spin 457us, R3 relaxed-spin 233us, R4 ticket 152us). Dead end.
//  - R5 (185.6us): 1 block/batch, zero sync. rocprof: kernel ~30us; ~156us is
//    the harness's 2x 512MiB workspace-poison fills (fixed cost). 128 blocks =
//    half the CUs idle -> ~4.5 TB/s (per-CU streaming cap ~25 GB/s).
//  - R6 (186.3us, neutral): B*4-band split, 512 blocks x 1024 thr, all CUs.
//    Split gain (if any) offset by +1 dispatch/gap. Residual over floor ~6us.
//  - R7 (this): non-temporal loads. The poison fills stream 1 GiB of writes
//    through L2/L3 right before our read; each input byte is read ONCE and
//    L3 is flushed between iterations -> caching loads only add allocate/
//    writeback contention. NT loads ('nt' flag) skip allocation. Also 4
//    independent accumulator chains (output is int coords -> FP order free).
//    Structural floor: 156 (fills) + ~20 (134MB stream) + ~4 (finalize) ~ 180.

#define H 512
#define W 512

typedef float f32x4 __attribute__((ext_vector_type(4)));

__global__ __launch_bounds__(1024) void cell_sums(
    const float* __restrict__ src, float* __restrict__ ws) {
  const int b = blockIdx.x >> 2;   // batch
  const int gr = blockIdx.x & 3;   // grid row band (128 rows)
  const int t = threadIdx.x;
  const f32x4* base =
      (const f32x4*)(src + (size_t)b * (H * W) + (size_t)gr * 128 * W);

  // Band = 16384 float4. f = t + 1024*k -> col4 = f & 127 = t & 127 is
  // CONSTANT per thread -> fixed grid column gc = (t&127)>>5 -> scalar
  // accumulators only, no indexed arrays. 4 chains for ILP.
  float s0 = 0.0f, s1 = 0.0f, s2 = 0.0f, s3 = 0.0f;
#pragma unroll
  for (int k = 0; k < 16; k += 4) {
    f32x4 v0 = __builtin_nontemporal_load(&base[t + 1024 * (k + 0)]);
    f32x4 v1 = __builtin_nontemporal_load(&base[t + 1024 * (k + 1)]);
    f32x4 v2 = __builtin_nontemporal_load(&base[t + 1024 * (k + 2)]);
    f32x4 v3 = __builtin_nontemporal_load(&base[t + 1024 * (k + 3)]);
    s0 += (v0[0] + v0[1]) + (v0[2] + v0[3]);
    s1 += (v1[0] + v1[1]) + (v1[2] + v1[3]);
    s2 += (v2[0] + v2[1]) + (v2[2] + v2[3]);
    s3 += (v3[0] + v3[1]) + (v3[2] + v3[3]);
  }
  float s = (s0 + s1) + (s2 + s3);

  // Within a 32-lane segment all lanes share gc (seg*32 % 128 = (seg&3)*32).
#pragma unroll
  for (int off = 16; off > 0; off >>= 1) s += __shfl_down(s, off, 32);

  __shared__ float seg_sums[32];  // [segment]; segment's gc = seg & 3
  const int seg = t >> 5;
  if ((t & 31) == 0) seg_sums[seg] = s;
  __syncthreads();

  // 8 segments per grid column; thread gc<4 sums its column's segments.
  if (t < 4) {
    float c = 0.0f;
#pragma unroll
    for (int j = 0; j < 8; ++j) c += seg_sums[j * 4 + t];
    ws[b * 16 + gr * 4 + t] = c;  // cell sum S[gr][gc=t]
  }
}

__global__ void finalize(const float* __restrict__ ws, int* __restrict__ out,
                         int B) {
  const int b = blockIdx.x * blockDim.x + threadIdx.x;
  if (b >= B) return;

  float S[16];
  const f32x4* w4 = (const f32x4*)(ws + (size_t)b * 16);
#pragma unroll
  for (int i = 0; i < 4; ++i) {
    f32x4 v = w4[i];
    S[i * 4 + 0] = v[0];
    S[i * 4 + 1] = v[1];
    S[i * 4 + 2] = v[2];
    S[i * 4 + 3] = v[3];
  }

  // 3x3 window sums, n=2; strict '>' keeps lowest flattened index on ties
  // (matches jax.lax.top_k).
  float best = -__builtin_inff();
  int bi = 0;
#pragma unroll
  for (int i = 0; i < 2; ++i)
#pragma unroll
    for (int j = 0; j < 2; ++j) {
      float wsum = 0.0f;
#pragma unroll
      for (int di = 0; di < 3; ++di)
#pragma unroll
        for (int dj = 0; dj < 3; ++dj) wsum += S[(i + di) * 4 + (j + dj)];
      if (wsum > best) {
        best = wsum;
        bi = i * 2 + j;
      }
    }
  out[b * 2 + 0] = bi >> 1;  // row
  out[b * 2 + 1] = bi & 1;   // col
}

extern "C" void kernel_launch(void* const* d_in, const int* in_sizes, int n_in,
                              void* d_out, int out_size, void* d_ws,
                              size_t ws_size, hipStream_t stream) {
  const float* src = (const float*)d_in[0];
  int* out = (int*)d_out;
  float* ws = (float*)d_ws;
  const int B = in_sizes[0] / (H * W);

  cell_sums<<<B * 4, 1024, 0, stream>>>(src, ws);
  finalize<<<(B + 127) / 128, 128, 0, stream>>>(ws, out, B);
}